// Round 9
// baseline (214.933 us; speedup 1.0000x reference)
//
#include <hip/hip_runtime.h>
#include <stdint.h>

typedef __attribute__((ext_vector_type(8))) short short8;
typedef __attribute__((ext_vector_type(4))) float f32x4;

#define B_      32
#define C_      3
#define HW_     364
#define D_      1152
#define NPS_    26
#define P_      676      // patches per sample
#define K_      588      // 3*14*14
#define KP_     608      // K padded to multiple of 32
#define KC_     19       // KP_/32 k-chunks
#define MT_     32       // patches per block (32 -> LDS 39,424 B -> 4 blocks/CU)
#define NT_     384      // cols per nb-iteration (x3 nb = full 1152)
#define AS_     616      // A row stride (bf16); b128 reads ~2-way bank alias only (free)
#define NP_     21632    // B_*P_
#define GRID_   676      // NP_/MT_ ; each block does all 1152 cols
#define NT16_   72       // D_/16

static __device__ __forceinline__ unsigned short f2bf(float x) {
  unsigned u = __float_as_uint(x);
  u += 0x7fffu + ((u >> 16) & 1u);      // round-to-nearest-even
  return (unsigned short)(u >> 16);
}

// ---- pack conv_w into fragment-major bf16, K zero-padded to 608 ----
// layout: idx = ((ntile*19 + kc)*64 + lane)*8 + e
//   value = w[n=ntile*16+(lane&15)][k=kc*32+(lane>>4)*8+e]
__global__ void prep_weights(const float* __restrict__ w,
                             unsigned short* __restrict__ whi) {
  int idx = blockIdx.x * 256 + threadIdx.x;
  if (idx >= NT16_ * KC_ * 64 * 8) return;
  int e    = idx & 7;
  int lane = (idx >> 3) & 63;
  int t    = idx >> 9;               // ntile*19 + kc
  int kc   = t % KC_;
  int nt   = t / KC_;
  int n = nt * 16 + (lane & 15);
  int k = kc * 32 + (lane >> 4) * 8 + e;
  float x = (k < K_) ? w[n * K_ + k] : 0.0f;
  whi[idx] = f2bf(x);
}

// ---- replicate reference bucketize exactly; mask dtype detected from word0 ----
__global__ void prep_pos(const void* __restrict__ maskp, int* __restrict__ pos_ids) {
  const int word0 = ((const int*)maskp)[0];
  int mode;                       // 0 = int32, 1 = byte, 2 = float
  if (word0 == 1) mode = 0;
  else if (word0 == 0x3F800000) mode = 2;
  else mode = 1;

  int idx = blockIdx.x * 256 + threadIdx.x;
  if (idx >= NP_) return;
  const int b = idx / P_;
  const int p = idx - b * P_;
  const int base = b * P_;

  auto get = [&](int i) -> int {
    if (mode == 0) return ((const int*)maskp)[base + i];
    if (mode == 1) return (int)((const unsigned char*)maskp)[base + i];
    return ((const float*)maskp)[base + i] != 0.0f ? 1 : 0;
  };

  int outp = 0;
  if (get(p)) {
    int nbh = 0, nbw = 0;
    #pragma unroll
    for (int r = 0; r < NPS_; ++r) nbh += get(r * NPS_);
    #pragma unroll
    for (int c = 0; c < NPS_; ++c) nbw += get(c);
    const int pr = p / NPS_;
    const int pc = p - pr * NPS_;
    const float eps = 1.0f - 1e-6f;
    const float fh = (float)((double)pr / (double)nbh) * eps;
    const float fw = (float)((double)pc / (double)nbw) * eps;
    int bh = 0, bw = 0;
    #pragma unroll
    for (int k = 1; k < NPS_; ++k) {
      const float bnd = (float)((double)k / (double)NPS_);
      bh += (bnd <= fh) ? 1 : 0;
      bw += (bnd <= fw) ? 1 : 0;
    }
    outp = bh * NPS_ + bw;
  }
  pos_ids[idx] = outp;
}

// ---- fused: stage 32-patch strip once, compute ALL 1152 cols (nb=0..2) ----
// __launch_bounds__(512,8): 8 waves/EU target -> VGPR cap 64 -> with 4 blocks/CU
// (LDS 39,424 x4 = 157,696 <= 160K) the CU runs at full 32-wave occupancy.
__global__ __launch_bounds__(512, 8)
void fused_embed(const float* __restrict__ pix,
                 const unsigned short* __restrict__ whi,
                 const float* __restrict__ bias,
                 const float* __restrict__ pos_emb,
                 const int* __restrict__ pos_ids,
                 float* __restrict__ out) {
  __shared__ __align__(16) unsigned short Ahi[MT_ * AS_];

  const int mb  = blockIdx.x;
  const int P0  = mb * MT_;
  const int tid = threadIdx.x;

  // ---- stage A strip: 32 patches x K(588) as bf16 in LDS (1344 tasks) ----
  for (int task = tid; task < 42 * MT_; task += 512) {
    const int s  = task >> 5;          // 0..41 = c*14+rr
    const int p  = task & 31;
    const int c  = s / 14;
    const int rr = s - c * 14;
    const int patch = P0 + p;
    const int b  = patch / P_;
    const int pp = patch - b * P_;
    const int pr = pp / NPS_;
    const int pc = pp - pr * NPS_;
    const float* sr = pix + ((size_t)(b * C_ + c) * HW_ + pr * 14 + rr) * HW_ + pc * 14;
    unsigned* dh = (unsigned*)&Ahi[p * AS_ + c * 196 + rr * 14];
    #pragma unroll
    for (int j = 0; j < 7; ++j)
      dh[j] = (unsigned)f2bf(sr[2 * j]) | ((unsigned)f2bf(sr[2 * j + 1]) << 16);
  }
  // zero K-pad region [588, 616)
  for (int i = tid; i < MT_ * 14; i += 512) {
    const int p = i / 14;
    const int k = K_ + (i - p * 14) * 2;
    *(unsigned*)(&Ahi[p * AS_ + k]) = 0u;
  }
  __syncthreads();

  const int lane = tid & 63;
  const int wid  = tid >> 6;            // 0..7, each wave owns 48 cols per nb
  const int l15  = lane & 15;
  const int lk8  = (lane >> 4) << 3;
  const int r4   = (lane >> 4) * 4;

  #pragma unroll 1
  for (int nb = 0; nb < 3; ++nb) {
    const int ntbase = nb * 24 + wid * 3;

    f32x4 acc[2][3];
    #pragma unroll
    for (int mi = 0; mi < 2; ++mi)
      #pragma unroll
      for (int ni = 0; ni < 3; ++ni)
        acc[mi][ni] = (f32x4)0.0f;

    // ---- K loop: single-buffered frags, TLP (8 waves/SIMD) hides latency ----
    #pragma unroll 1
    for (int kc = 0; kc < KC_; ++kc) {
      const int ko = kc * 32 + lk8;
      short8 ah0 = *(const short8*)&Ahi[l15 * AS_ + ko];
      short8 ah1 = *(const short8*)&Ahi[(16 + l15) * AS_ + ko];
      short8 bh0 = *(const short8*)(whi + (((ntbase + 0) * KC_ + kc) * 64 + lane) * 8);
      short8 bh1 = *(const short8*)(whi + (((ntbase + 1) * KC_ + kc) * 64 + lane) * 8);
      short8 bh2 = *(const short8*)(whi + (((ntbase + 2) * KC_ + kc) * 64 + lane) * 8);
      acc[0][0] = __builtin_amdgcn_mfma_f32_16x16x32_bf16(ah0, bh0, acc[0][0], 0, 0, 0);
      acc[0][1] = __builtin_amdgcn_mfma_f32_16x16x32_bf16(ah0, bh1, acc[0][1], 0, 0, 0);
      acc[0][2] = __builtin_amdgcn_mfma_f32_16x16x32_bf16(ah0, bh2, acc[0][2], 0, 0, 0);
      acc[1][0] = __builtin_amdgcn_mfma_f32_16x16x32_bf16(ah1, bh0, acc[1][0], 0, 0, 0);
      acc[1][1] = __builtin_amdgcn_mfma_f32_16x16x32_bf16(ah1, bh1, acc[1][1], 0, 0, 0);
      acc[1][2] = __builtin_amdgcn_mfma_f32_16x16x32_bf16(ah1, bh2, acc[1][2], 0, 0, 0);
    }

    // ---- epilogue for this nb: + bias + pos_emb[pos_ids] ----
    const int colb = nb * NT_ + wid * 48;
    float cb0 = bias[colb + l15];
    float cb1 = bias[colb + 16 + l15];
    float cb2 = bias[colb + 32 + l15];
    #pragma unroll
    for (int mi = 0; mi < 2; ++mi) {
      #pragma unroll
      for (int r = 0; r < 4; ++r) {
        const int patch = P0 + mi * 16 + r4 + r;
        const int pid = pos_ids[patch];
        const float* pe = pos_emb + (size_t)pid * D_;
        float* po = out + (size_t)patch * D_;
        po[colb + l15]      = acc[mi][0][r] + cb0 + pe[colb + l15];
        po[colb + 16 + l15] = acc[mi][1][r] + cb1 + pe[colb + 16 + l15];
        po[colb + 32 + l15] = acc[mi][2][r] + cb2 + pe[colb + 32 + l15];
      }
    }
  }
}

extern "C" void kernel_launch(void* const* d_in, const int* in_sizes, int n_in,
                              void* d_out, int out_size, void* d_ws, size_t ws_size,
                              hipStream_t stream) {
  const float* pix            = (const float*)d_in[0];
  const void* mask            = (const void*)d_in[1];
  const float* conv_w         = (const float*)d_in[2];
  const float* conv_b         = (const float*)d_in[3];
  const float* pos_emb        = (const float*)d_in[4];
  float* out                  = (float*)d_out;

  char* ws = (char*)d_ws;
  unsigned short* whi = (unsigned short*)ws;                 // 1,400,832 B
  int* pos_ids        = (int*)(ws + 1400832);                // 86,528 B

  prep_weights<<<(NT16_ * KC_ * 64 * 8 + 255) / 256, 256, 0, stream>>>(conv_w, whi);
  prep_pos<<<(NP_ + 255) / 256, 256, 0, stream>>>(mask, pos_ids);
  fused_embed<<<GRID_, 512, 0, stream>>>(pix, whi, conv_b, pos_emb, pos_ids, out);
}

// Round 10
// 202.902 us; speedup vs baseline: 1.0593x; 1.0593x over previous
//
#include <hip/hip_runtime.h>
#include <stdint.h>

typedef __attribute__((ext_vector_type(8))) short short8;
typedef __attribute__((ext_vector_type(4))) float f32x4;

#define B_      32
#define C_      3
#define HW_     364
#define D_      1152
#define NPS_    26
#define P_      676      // patches per sample
#define K_      588      // 3*14*14
#define KP_     608      // K padded to multiple of 32
#define KC_     19       // KP_/32 k-chunks
#define MT_     32       // patches per block -> LDS 39,424 B
#define NT_     384      // cols per block
#define AS_     616      // A row stride (bf16); 308 dwords -> 8-bank spread, ~2-way only
#define NP_     21632    // B_*P_
#define MBLK_   676      // NP_/MT_
#define NBLK_   3        // D_/NT_
#define NWORK_  2028     // MBLK_*NBLK_
#define CHUNK_  254      // NWORK_/8 rounded up
#define GRID_   2032     // 8*CHUNK_ (4 dummies)
#define NT16_   72       // D_/16

static __device__ __forceinline__ unsigned short f2bf(float x) {
  unsigned u = __float_as_uint(x);
  u += 0x7fffu + ((u >> 16) & 1u);      // round-to-nearest-even
  return (unsigned short)(u >> 16);
}

// ---- pack conv_w into fragment-major bf16, K zero-padded to 608 ----
// layout: idx = ((ntile*19 + kc)*64 + lane)*8 + e
//   value = w[n=ntile*16+(lane&15)][k=kc*32+(lane>>4)*8+e]
__global__ void prep_weights(const float* __restrict__ w,
                             unsigned short* __restrict__ whi) {
  int idx = blockIdx.x * 256 + threadIdx.x;
  if (idx >= NT16_ * KC_ * 64 * 8) return;
  int e    = idx & 7;
  int lane = (idx >> 3) & 63;
  int t    = idx >> 9;               // ntile*19 + kc
  int kc   = t % KC_;
  int nt   = t / KC_;
  int n = nt * 16 + (lane & 15);
  int k = kc * 32 + (lane >> 4) * 8 + e;
  float x = (k < K_) ? w[n * K_ + k] : 0.0f;
  whi[idx] = f2bf(x);
}

// ---- replicate reference bucketize exactly; mask dtype detected from word0 ----
__global__ void prep_pos(const void* __restrict__ maskp, int* __restrict__ pos_ids) {
  const int word0 = ((const int*)maskp)[0];
  int mode;                       // 0 = int32, 1 = byte, 2 = float
  if (word0 == 1) mode = 0;
  else if (word0 == 0x3F800000) mode = 2;
  else mode = 1;

  int idx = blockIdx.x * 256 + threadIdx.x;
  if (idx >= NP_) return;
  const int b = idx / P_;
  const int p = idx - b * P_;
  const int base = b * P_;

  auto get = [&](int i) -> int {
    if (mode == 0) return ((const int*)maskp)[base + i];
    if (mode == 1) return (int)((const unsigned char*)maskp)[base + i];
    return ((const float*)maskp)[base + i] != 0.0f ? 1 : 0;
  };

  int outp = 0;
  if (get(p)) {
    int nbh = 0, nbw = 0;
    #pragma unroll
    for (int r = 0; r < NPS_; ++r) nbh += get(r * NPS_);
    #pragma unroll
    for (int c = 0; c < NPS_; ++c) nbw += get(c);
    const int pr = p / NPS_;
    const int pc = p - pr * NPS_;
    const float eps = 1.0f - 1e-6f;
    const float fh = (float)((double)pr / (double)nbh) * eps;
    const float fw = (float)((double)pc / (double)nbw) * eps;
    int bh = 0, bw = 0;
    #pragma unroll
    for (int k = 1; k < NPS_; ++k) {
      const float bnd = (float)((double)k / (double)NPS_);
      bh += (bnd <= fh) ? 1 : 0;
      bw += (bnd <= fw) ? 1 : 0;
    }
    outp = bh * NPS_ + bw;
  }
  pos_ids[idx] = outp;
}

struct Frags { short8 ah[2]; short8 bh[3]; };

__device__ __forceinline__ void load_b(Frags& f, int kc, int ntbase, int lane,
                                       const unsigned short* __restrict__ whi) {
  #pragma unroll
  for (int ni = 0; ni < 3; ++ni) {
    const int off = (((ntbase + ni) * KC_ + kc) * 64 + lane) * 8;
    f.bh[ni] = *(const short8*)(whi + off);
  }
}

__device__ __forceinline__ void load_a(Frags& f, int kc, int l15, int lk8,
                                       const unsigned short* Ahi_) {
  const int ko = kc * 32 + lk8;
  f.ah[0] = *(const short8*)&Ahi_[l15 * AS_ + ko];
  f.ah[1] = *(const short8*)&Ahi_[(16 + l15) * AS_ + ko];
}

__device__ __forceinline__ void load_frags(Frags& f, int kc, int l15, int lk8,
                                           int ntbase, int lane,
                                           const unsigned short* Ahi_,
                                           const unsigned short* __restrict__ whi) {
  load_a(f, kc, l15, lk8, Ahi_);
  load_b(f, kc, ntbase, lane, whi);
}

__device__ __forceinline__ void mfma_frags(f32x4 acc[2][3], const Frags& f) {
  #pragma unroll
  for (int mi = 0; mi < 2; ++mi)
    #pragma unroll
    for (int ni = 0; ni < 3; ++ni)
      acc[mi][ni] = __builtin_amdgcn_mfma_f32_16x16x32_bf16(f.ah[mi], f.bh[ni], acc[mi][ni], 0, 0, 0);
}

// ---- fused: stage 32-patch strip, 384 cols per block, 2-stage reg pipeline ----
// LDS 39,424 B; __launch_bounds__(512,6) -> 3 blocks/CU resident, 2028-deep queue.
__global__ __launch_bounds__(512, 6)
void fused_embed(const float* __restrict__ pix,
                 const unsigned short* __restrict__ whi,
                 const float* __restrict__ bias,
                 const float* __restrict__ pos_emb,
                 const int* __restrict__ pos_ids,
                 float* __restrict__ out) {
  __shared__ __align__(16) unsigned short Ahi[MT_ * AS_];

  // XCD-chunked swizzle (hw xcd = blockIdx % 8): consecutive w on one XCD;
  // the 3 nb-blocks of one mb-strip are w-adjacent -> share L2 pixel lines.
  const int bid0 = blockIdx.x;
  const int w = (bid0 & 7) * CHUNK_ + (bid0 >> 3);
  if (w >= NWORK_) return;
  const int mb  = w / NBLK_;
  const int nb  = w - mb * NBLK_;
  const int P0  = mb * MT_;
  const int tid = threadIdx.x;
  const int lane = tid & 63;
  const int wid  = tid >> 6;            // 0..7, each wave owns 48 cols
  const int l15  = lane & 15;
  const int lk8  = (lane >> 4) << 3;
  const int ntbase = nb * 24 + wid * 3;

  // prefetch f0's B fragments (global, LDS-independent) before the barrier
  Frags f0, f1;
  load_b(f0, 0, ntbase, lane, whi);

  // ---- stage A strip: 32 patches x K(588) as bf16 in LDS (1344 tasks) ----
  for (int task = tid; task < 42 * MT_; task += 512) {
    const int s  = task >> 5;          // 0..41 = c*14+rr
    const int p  = task & 31;
    const int c  = s / 14;
    const int rr = s - c * 14;
    const int patch = P0 + p;
    const int b  = patch / P_;
    const int pp = patch - b * P_;
    const int pr = pp / NPS_;
    const int pc = pp - pr * NPS_;
    const float* sr = pix + ((size_t)(b * C_ + c) * HW_ + pr * 14 + rr) * HW_ + pc * 14;
    unsigned* dh = (unsigned*)&Ahi[p * AS_ + c * 196 + rr * 14];
    #pragma unroll
    for (int j = 0; j < 7; ++j)
      dh[j] = (unsigned)f2bf(sr[2 * j]) | ((unsigned)f2bf(sr[2 * j + 1]) << 16);
  }
  // zero K-pad region [588, 616)
  for (int i = tid; i < MT_ * 14; i += 512) {
    const int p = i / 14;
    const int k = K_ + (i - p * 14) * 2;
    *(unsigned*)(&Ahi[p * AS_ + k]) = 0u;
  }
  __syncthreads();

  f32x4 acc[2][3];
  #pragma unroll
  for (int mi = 0; mi < 2; ++mi)
    #pragma unroll
    for (int ni = 0; ni < 3; ++ni)
      acc[mi][ni] = (f32x4)0.0f;

  // ---- K loop, 2-stage software pipeline (proven R5/R6 structure) ----
  load_a(f0, 0, l15, lk8, Ahi);
  #pragma unroll 1
  for (int kc = 0; kc + 2 < KC_; kc += 2) {
    load_frags(f1, kc + 1, l15, lk8, ntbase, lane, Ahi, whi);
    mfma_frags(acc, f0);
    load_frags(f0, kc + 2, l15, lk8, ntbase, lane, Ahi, whi);
    mfma_frags(acc, f1);
  }
  mfma_frags(acc, f0);   // kc = 18

  // ---- epilogue: + bias + pos_emb[pos_ids] ----
  const int colb = nb * NT_ + wid * 48;
  float cb0 = bias[colb + l15];
  float cb1 = bias[colb + 16 + l15];
  float cb2 = bias[colb + 32 + l15];
  const int r4 = (lane >> 4) * 4;
  #pragma unroll
  for (int mi = 0; mi < 2; ++mi) {
    #pragma unroll
    for (int r = 0; r < 4; ++r) {
      const int patch = P0 + mi * 16 + r4 + r;
      const int pid = pos_ids[patch];
      const float* pe = pos_emb + (size_t)pid * D_;
      float* po = out + (size_t)patch * D_;
      po[colb + l15]      = acc[mi][0][r] + cb0 + pe[colb + l15];
      po[colb + 16 + l15] = acc[mi][1][r] + cb1 + pe[colb + 16 + l15];
      po[colb + 32 + l15] = acc[mi][2][r] + cb2 + pe[colb + 32 + l15];
    }
  }
}

extern "C" void kernel_launch(void* const* d_in, const int* in_sizes, int n_in,
                              void* d_out, int out_size, void* d_ws, size_t ws_size,
                              hipStream_t stream) {
  const float* pix            = (const float*)d_in[0];
  const void* mask            = (const void*)d_in[1];
  const float* conv_w         = (const float*)d_in[2];
  const float* conv_b         = (const float*)d_in[3];
  const float* pos_emb        = (const float*)d_in[4];
  float* out                  = (float*)d_out;

  char* ws = (char*)d_ws;
  unsigned short* whi = (unsigned short*)ws;                 // 1,400,832 B
  int* pos_ids        = (int*)(ws + 1400832);                // 86,528 B

  prep_weights<<<(NT16_ * KC_ * 64 * 8 + 255) / 256, 256, 0, stream>>>(conv_w, whi);
  prep_pos<<<(NP_ + 255) / 256, 256, 0, stream>>>(mask, pos_ids);
  fused_embed<<<GRID_, 512, 0, stream>>>(pix, whi, conv_b, pos_emb, pos_ids, out);
}